// Round 8
// baseline (1172.899 us; speedup 1.0000x reference)
//
#include <hip/hip_runtime.h>
#include <hip/hip_fp16.h>
#include <hip/hip_cooperative_groups.h>

namespace cg = cooperative_groups;

// DGCF single-layer, 2 routing iters (MI355X). fp32 in / fp32 out.
// R22: whole pipeline fused into ONE cooperative kernel (8 grid.sync
// phases). Rationale: all kernels < 45us individually; remaining cost is
// structural -- 9 serial dispatches (ramp+drain each) + rank round-trip
// (6.4MB) + eh re-read (3.2MB) that exist only because count/scan/scatter
// are split across dispatch boundaries. Phases:
//  P0 zero deg0 | P1 count (rank HELD IN REGS) | P2 scan_local || prep
//  (overlapped) | P3 scan_add2 | P4 scatter-from-regs | P5 zacc+headfill |
//  P6 attdot_sm | P7 deg_y1 | P8 outk.
// Grid 1024x256, __launch_bounds__(256,4) -> 4 blocks/CU co-residency
// guaranteed. All phase BODIES are byte-identical to R21 (shared __device__
// fns); R21's 9-dispatch path kept as fallback if coop launch errors.
// Unchanged logic (passing since R19-R21): rank-from-count atomic-free
// scatter, tail-only scatter + coalesced head fill, zacc/outk 2-node x
// 32-lane full-line gathers, per-edge fused softmax, Y1i[n][64].

#define NUSERS 30000
#define NN     60000
#define EE     800000
#define NCHUNK (EE / 4)                 // 200000 int4 edge chunks
#define SCAN_B ((NN + 255) / 256)       // 235 scan chunks
#define EV_B   ((EE / 4 + 255) / 256)   // 782 (fallback)
#define NW1_B  ((NN + 1 + 3) / 4)       // 15001 prep node-groups
#define NW_B   ((NN + 3) / 4)           // 15000 deg_y1 node-groups
#define N8_B   ((NN + 7) / 8)           // 7500 zacc/outk node-groups
#define GRID   1024                     // 4 blocks/CU x 256 CUs

__device__ __forceinline__ float getX(const float* __restrict__ Gu,
                                      const float* __restrict__ Gi,
                                      int n, int c) {
    return (n < NUSERS) ? Gu[n * 64 + c] : Gi[(n - NUSERS) * 64 + c];
}

__device__ __forceinline__ int clampN(int n) {
    return ((unsigned)n < (unsigned)NN) ? n : 0;
}

__device__ __forceinline__ __half2 bch2(float f) {
    return __builtin_bit_cast(__half2, f);
}

// ==== phase bodies (shared by mega kernel and fallback dispatches) ====

__device__ __forceinline__ void scanlocal_body(int chunk, int tid,
        const int* __restrict__ deg0, int* __restrict__ offsets,
        int* __restrict__ bsum, int* wsum) {
    int gid = chunk * 256 + tid;
    int lane = tid & 63, w = tid >> 6;
    int vdeg = (gid < NN) ? deg0[gid] : 0;
    int x = vdeg;
    #pragma unroll
    for (int d = 1; d < 64; d <<= 1) {
        int y = __shfl_up(x, d, 64);
        if (lane >= d) x += y;
    }
    if (lane == 63) wsum[w] = x;
    __syncthreads();
    int wpre = 0;
    #pragma unroll
    for (int j = 0; j < 4; ++j) wpre += (j < w) ? wsum[j] : 0;
    int incl = x + wpre;
    if (gid < NN) offsets[gid] = incl - vdeg;
    if (tid == 255) bsum[chunk] = incl;
}

__device__ __forceinline__ void scanadd2_body(int chunk, int tid,
        int* __restrict__ offsets, const int* __restrict__ bsum,
        int* wsum, int* bpre) {
    int lane = tid & 63, w = tid >> 6;
    int vv = (tid < SCAN_B) ? bsum[tid] : 0;
    int x = vv;
    #pragma unroll
    for (int d = 1; d < 64; d <<= 1) {
        int y = __shfl_up(x, d, 64);
        if (lane >= d) x += y;
    }
    if (lane == 63) wsum[w] = x;
    __syncthreads();
    int wpre = 0;
    #pragma unroll
    for (int j = 0; j < 4; ++j) wpre += (j < w) ? wsum[j] : 0;
    if (tid == chunk) *bpre = x + wpre - vv;   // exclusive prefix of this chunk
    __syncthreads();
    int gid = chunk * 256 + tid;
    if (gid < NN) offsets[gid] += *bpre;
    if (gid == 0) offsets[NN] = EE;
}

__device__ __forceinline__ void prep_body(int n, int lane,
        const float* __restrict__ Gu, const float* __restrict__ Gi,
        const int* __restrict__ deg0,
        __half* __restrict__ Ytab, __half* __restrict__ Ttab) {
    float x = (n < NN) ? getX(Gu, Gi, n, lane) : 0.f;
    float sx = x * x;
    #pragma unroll
    for (int m = 1; m < 16; m <<= 1) sx += __shfl_xor(sx, m, 64);  // 16-ch intent group
    float invx = rsqrtf(fmaxf(sx, 1e-12f));
    float d0 = rsqrtf(fmaxf(0.25f * (float)((n < NN) ? deg0[n] : 1), 1e-30f));
    size_t a = (size_t)n * 64 + lane;
    Ytab[a] = __float2half(d0 * x);          // iter-0 Y (scores==0.25 folded)
    Ttab[a] = __float2half(tanhf(x * invx)); // tanh of l2norm(x) per intent
}

__device__ __forceinline__ void zacc_body(int n, int cc,
        const int* __restrict__ offsets, const int* __restrict__ csr_tail,
        const __half* __restrict__ Ytab, __half* __restrict__ ZN,
        int* __restrict__ csr_head) {
    int s0 = offsets[n], s1 = offsets[n + 1];
    for (int k = s0 + cc; k < s1; k += 32) csr_head[k] = n;  // coalesced head fill
    float accx = 0.f, accy = 0.f;
    for (int base = s0; base < s1; base += 4) {
        #pragma unroll
        for (int u = 0; u < 4; ++u) {
            int kk = base + u;
            bool act = kk < s1;
            int kc = act ? kk : s0;              // in-bounds; deg >= 1 always
            int t = act ? csr_tail[kc] : NN;     // NN = zero row
            __half2 y = *(const __half2*)(Ytab + (size_t)t * 64 + cc * 2);
            float2 yf = __half22float2(y);
            accx += yf.x; accy += yf.y;
        }
    }
    // per-intent l2 norm: 8-lane group = 16 channels = 1 intent
    float ss = accx * accx + accy * accy;
    ss += __shfl_xor(ss, 1, 64);
    ss += __shfl_xor(ss, 2, 64);
    ss += __shfl_xor(ss, 4, 64);
    float inv = rsqrtf(fmaxf(ss, 1e-12f));
    *(__half2*)(ZN + (size_t)n * 64 + cc * 2) =
        __floats2half2_rn(accx * inv, accy * inv);
}

__device__ __forceinline__ void attdot_body(int k,
        const int* __restrict__ csr_head, const int* __restrict__ csr_tail,
        const __half* __restrict__ ZN, const __half* __restrict__ Ttab,
        __half* __restrict__ s4) {
    int h = csr_head[k], t = csr_tail[k];
    const float4* zp = (const float4*)(ZN + (size_t)h * 64);
    const float4* tp = (const float4*)(Ttab + (size_t)t * 64);
    float dot[4];
    #pragma unroll
    for (int i = 0; i < 4; ++i) {
        float4 za = zp[2 * i], zb = zp[2 * i + 1];
        float4 ta = tp[2 * i], tb = tp[2 * i + 1];
        __half2 acc = __floats2half2_rn(0.f, 0.f);
        acc = __hfma2(bch2(za.x), bch2(ta.x), acc);
        acc = __hfma2(bch2(za.y), bch2(ta.y), acc);
        acc = __hfma2(bch2(za.z), bch2(ta.z), acc);
        acc = __hfma2(bch2(za.w), bch2(ta.w), acc);
        acc = __hfma2(bch2(zb.x), bch2(tb.x), acc);
        acc = __hfma2(bch2(zb.y), bch2(tb.y), acc);
        acc = __hfma2(bch2(zb.z), bch2(tb.z), acc);
        acc = __hfma2(bch2(zb.w), bch2(tb.w), acc);
        float2 f = __half22float2(acc);
        dot[i] = f.x + f.y;
    }
    float mx = fmaxf(fmaxf(dot[0], dot[1]), fmaxf(dot[2], dot[3]));
    float e0 = __expf(dot[0] - mx), e1 = __expf(dot[1] - mx);
    float e2 = __expf(dot[2] - mx), e3 = __expf(dot[3] - mx);
    float inv = 1.f / (e0 + e1 + e2 + e3);
    __half2 q01 = __floats2half2_rn(e0 * inv, e1 * inv);
    __half2 q23 = __floats2half2_rn(e2 * inv, e3 * inv);
    int2 st;
    st.x = __builtin_bit_cast(int, q01);
    st.y = __builtin_bit_cast(int, q23);
    *(int2*)(s4 + (size_t)k * 4) = st;
}

__device__ __forceinline__ void degy1_body(int n, int lane,
        const int* __restrict__ offsets, const __half* __restrict__ s4,
        float* __restrict__ dcol1,
        const float* __restrict__ Gu, const float* __restrict__ Gi,
        __half* __restrict__ Y1i) {
    int s0 = offsets[n], s1 = offsets[n + 1];
    float sum0 = 0.f, sum1 = 0.f, sum2 = 0.f, sum3 = 0.f;
    for (int k = s0 + lane; k < s1; k += 64) {
        int2 raw = *(const int2*)(s4 + (size_t)k * 4);
        float2 fa = __half22float2(__builtin_bit_cast(__half2, raw.x));
        float2 fb = __half22float2(__builtin_bit_cast(__half2, raw.y));
        sum0 += fa.x; sum1 += fa.y; sum2 += fb.x; sum3 += fb.y;
    }
    #pragma unroll
    for (int m = 1; m < 64; m <<= 1) {
        sum0 += __shfl_xor(sum0, m, 64);
        sum1 += __shfl_xor(sum1, m, 64);
        sum2 += __shfl_xor(sum2, m, 64);
        sum3 += __shfl_xor(sum3, m, 64);
    }
    int i = lane >> 4;                           // intent of channel 'lane'
    float dsel = (i == 0) ? sum0 : (i == 1) ? sum1 : (i == 2) ? sum2 : sum3;
    float d = rsqrtf(fmaxf(dsel, 1e-30f));
    if (lane < 4) {
        float ds = (lane == 0) ? sum0 : (lane == 1) ? sum1 : (lane == 2) ? sum2 : sum3;
        dcol1[n * 4 + lane] = rsqrtf(fmaxf(ds, 1e-30f));
    }
    float x = getX(Gu, Gi, n, lane);
    Y1i[(size_t)n * 64 + lane] = __float2half(d * x);
}

__device__ __forceinline__ void outk_body(int n, int cc,
        const int* __restrict__ offsets, const int* __restrict__ csr_tail,
        const __half* __restrict__ Y1i, const __half* __restrict__ s4,
        const float* __restrict__ dcol1,
        const float* __restrict__ Gu, const float* __restrict__ Gi,
        float* __restrict__ out) {
    int s0 = offsets[n], s1 = offsets[n + 1];
    float accx = 0.f, accy = 0.f;
    for (int base = s0; base < s1; base += 4) {
        #pragma unroll
        for (int u = 0; u < 4; ++u) {
            int kk = base + u;
            bool act = kk < s1;
            int kc = act ? kk : s0;              // in-bounds; deg >= 1 always
            int t = csr_tail[kc];
            int2 raw = *(const int2*)(s4 + (size_t)kc * 4);
            int word = (cc & 16) ? raw.y : raw.x;
            unsigned short us = (unsigned short)(word >> ((cc & 8) ? 16 : 0));
            float s = act ? __half2float(__builtin_bit_cast(__half, us)) : 0.f;
            __half2 y = *(const __half2*)(Y1i + (size_t)t * 64 + cc * 2);
            float2 yf = __half22float2(y);
            accx = fmaf(s, yf.x, accx);
            accy = fmaf(s, yf.y, accy);
        }
    }
    float d = dcol1[n * 4 + (cc >> 3)];
    int ch = cc * 2;
    const float* xr = (n < NUSERS) ? (Gu + (size_t)n * 64 + ch)
                                   : (Gi + (size_t)(n - NUSERS) * 64 + ch);
    float2 x2 = *(const float2*)xr;
    float2 o;
    o.x = 0.5f * (x2.x + d * accx);
    o.y = 0.5f * (x2.y + d * accy);
    *(float2*)(out + (size_t)n * 64 + ch) = o;
}

// ==== fused cooperative kernel: whole pipeline, 8 grid barriers ====
__global__ __launch_bounds__(256, 4) void mega(
        const int* __restrict__ eh, const int* __restrict__ et,
        const float* __restrict__ Gu, const float* __restrict__ Gi,
        int* __restrict__ deg0, int* __restrict__ offsets, int* __restrict__ bsum,
        int* __restrict__ csr_tail, int* __restrict__ csr_head,
        __half* __restrict__ Ytab, __half* __restrict__ Ttab,
        __half* __restrict__ ZN, __half* __restrict__ s4,
        float* __restrict__ dcol1, float* __restrict__ out) {
    cg::grid_group g = cg::this_grid();
    int tid = threadIdx.x;
    int gt = blockIdx.x * 256 + tid;
    __shared__ int wsum[4];
    __shared__ int bpre;

    // P0: zero deg0 (replaces hipMemsetAsync)
    for (int i = gt; i < NN; i += GRID * 256) deg0[i] = 0;
    g.sync();

    // P1: count + rank held in regs (rank array deleted)
    int4 hc = make_int4(0, 0, 0, 0), tt = make_int4(0, 0, 0, 0),
         rr = make_int4(0, 0, 0, 0);
    bool haveChunk = gt < NCHUNK;
    if (haveChunk) {
        int e4 = gt * 4;
        int4 h = *(const int4*)(eh + e4);
        int4 t = *(const int4*)(et + e4);
        hc.x = clampN(h.x); hc.y = clampN(h.y); hc.z = clampN(h.z); hc.w = clampN(h.w);
        tt.x = clampN(t.x); tt.y = clampN(t.y); tt.z = clampN(t.z); tt.w = clampN(t.w);
        rr.x = atomicAdd(&deg0[hc.x], 1);
        rr.y = atomicAdd(&deg0[hc.y], 1);
        rr.z = atomicAdd(&deg0[hc.z], 1);
        rr.w = atomicAdd(&deg0[hc.w], 1);
    }
    g.sync();

    // P2: scan_local (blocks 0..234) || prep tables (all blocks, grid-stride)
    if (blockIdx.x < SCAN_B)
        scanlocal_body(blockIdx.x, tid, deg0, offsets, bsum, wsum);
    for (int vb = blockIdx.x; vb < NW1_B; vb += GRID) {
        int n = vb * 4 + (tid >> 6);
        if (n <= NN) prep_body(n, tid & 63, Gu, Gi, deg0, Ytab, Ttab);
    }
    g.sync();

    // P3: scan_add2 (blocks 0..234)
    if (blockIdx.x < SCAN_B)
        scanadd2_body(blockIdx.x, tid, offsets, bsum, wsum, &bpre);
    g.sync();

    // P4: scatter from held regs (atomic-free, tail-only)
    if (haveChunk) {
        int s0 = offsets[hc.x] + rr.x;
        if ((unsigned)s0 < EE) csr_tail[s0] = tt.x;
        int s1 = offsets[hc.y] + rr.y;
        if ((unsigned)s1 < EE) csr_tail[s1] = tt.y;
        int s2 = offsets[hc.z] + rr.z;
        if ((unsigned)s2 < EE) csr_tail[s2] = tt.z;
        int s3 = offsets[hc.w] + rr.w;
        if ((unsigned)s3 < EE) csr_tail[s3] = tt.w;
    }
    g.sync();

    // P5: zacc + head fill (grid-stride over 7500 groups)
    for (int vb = blockIdx.x; vb < N8_B; vb += GRID) {
        int n = vb * 8 + (tid >> 5);
        if (n < NN) zacc_body(n, tid & 31, offsets, csr_tail, Ytab, ZN, csr_head);
    }
    g.sync();

    // P6: per-edge dots + softmax (grid-stride, one edge per lane)
    for (int k = gt; k < EE; k += GRID * 256)
        attdot_body(k, csr_head, csr_tail, ZN, Ttab, s4);
    g.sync();

    // P7: bucket sums -> dcol1 + Y1i rows (Y1i aliases Ytab; last Ytab read was P5)
    for (int vb = blockIdx.x; vb < NW_B; vb += GRID) {
        int n = vb * 4 + (tid >> 6);
        if (n < NN) degy1_body(n, tid & 63, offsets, s4, dcol1, Gu, Gi, Ytab);
    }
    g.sync();

    // P8: iter-1 propagate + finalize
    for (int vb = blockIdx.x; vb < N8_B; vb += GRID) {
        int n = vb * 8 + (tid >> 5);
        if (n < NN) outk_body(n, tid & 31, offsets, csr_tail, Ytab, s4, dcol1,
                              Gu, Gi, out);
    }
}

// ==== fallback dispatches (R21 path, used if coop launch errors) ====

__global__ void edge_count(const int* __restrict__ eh, int* __restrict__ deg0,
                           int* __restrict__ rank) {
    int e4 = (blockIdx.x * blockDim.x + threadIdx.x) * 4;
    if (e4 >= EE) return;
    int4 h = *(const int4*)(eh + e4);
    int4 r;
    r.x = atomicAdd(&deg0[clampN(h.x)], 1);
    r.y = atomicAdd(&deg0[clampN(h.y)], 1);
    r.z = atomicAdd(&deg0[clampN(h.z)], 1);
    r.w = atomicAdd(&deg0[clampN(h.w)], 1);
    *(int4*)(rank + e4) = r;
}

__global__ void scan_local(const int* __restrict__ deg0, int* __restrict__ offsets,
                           int* __restrict__ bsum) {
    __shared__ int wsum[4];
    scanlocal_body(blockIdx.x, threadIdx.x, deg0, offsets, bsum, wsum);
}

__global__ void scan_add2(int* __restrict__ offsets, const int* __restrict__ bsum) {
    __shared__ int wsum[4];
    __shared__ int bpre;
    scanadd2_body(blockIdx.x, threadIdx.x, offsets, bsum, wsum, &bpre);
}

__global__ void scatter_prep(const int* __restrict__ eh, const int* __restrict__ et,
                             const int* __restrict__ rank,
                             const int* __restrict__ offsets,
                             int* __restrict__ csr_tail,
                             const float* __restrict__ Gu, const float* __restrict__ Gi,
                             const int* __restrict__ deg0,
                             __half* __restrict__ Ytab, __half* __restrict__ Ttab) {
    if (blockIdx.x < EV_B) {
        int e4 = (blockIdx.x * 256 + threadIdx.x) * 4;
        if (e4 >= EE) return;
        int4 h = *(const int4*)(eh + e4);
        int4 t = *(const int4*)(et + e4);
        int4 r = *(const int4*)(rank + e4);
        int s0 = offsets[clampN(h.x)] + r.x;
        if ((unsigned)s0 < EE) csr_tail[s0] = clampN(t.x);
        int s1 = offsets[clampN(h.y)] + r.y;
        if ((unsigned)s1 < EE) csr_tail[s1] = clampN(t.y);
        int s2 = offsets[clampN(h.z)] + r.z;
        if ((unsigned)s2 < EE) csr_tail[s2] = clampN(t.z);
        int s3 = offsets[clampN(h.w)] + r.w;
        if ((unsigned)s3 < EE) csr_tail[s3] = clampN(t.w);
    } else {
        int n = (blockIdx.x - EV_B) * 4 + (threadIdx.x >> 6);
        if (n > NN) return;
        prep_body(n, threadIdx.x & 63, Gu, Gi, deg0, Ytab, Ttab);
    }
}

__global__ void zacc(const int* __restrict__ offsets, const int* __restrict__ csr_tail,
                     const __half* __restrict__ Ytab, __half* __restrict__ ZN,
                     int* __restrict__ csr_head) {
    int n = blockIdx.x * 8 + (threadIdx.x >> 5);
    if (n >= NN) return;
    zacc_body(n, threadIdx.x & 31, offsets, csr_tail, Ytab, ZN, csr_head);
}

__global__ void attdot_sm(const int* __restrict__ csr_head, const int* __restrict__ csr_tail,
                          const __half* __restrict__ ZN, const __half* __restrict__ Ttab,
                          __half* __restrict__ s4) {
    int k = blockIdx.x * 256 + threadIdx.x;
    if (k >= EE) return;
    attdot_body(k, csr_head, csr_tail, ZN, Ttab, s4);
}

__global__ void deg_y1(const int* __restrict__ offsets, const __half* __restrict__ s4,
                       float* __restrict__ dcol1,
                       const float* __restrict__ Gu, const float* __restrict__ Gi,
                       __half* __restrict__ Y1i) {
    int n = blockIdx.x * 4 + (threadIdx.x >> 6);
    if (n >= NN) return;
    degy1_body(n, threadIdx.x & 63, offsets, s4, dcol1, Gu, Gi, Y1i);
}

__global__ void outk(const int* __restrict__ offsets, const int* __restrict__ csr_tail,
                     const __half* __restrict__ Y1i, const __half* __restrict__ s4,
                     const float* __restrict__ dcol1,
                     const float* __restrict__ Gu, const float* __restrict__ Gi,
                     float* __restrict__ out) {
    int n = blockIdx.x * 8 + (threadIdx.x >> 5);
    if (n >= NN) return;
    outk_body(n, threadIdx.x & 31, offsets, csr_tail, Y1i, s4, dcol1, Gu, Gi, out);
}

// ---- launch ----

extern "C" void kernel_launch(void* const* d_in, const int* in_sizes, int n_in,
                              void* d_out, int out_size, void* d_ws, size_t ws_size,
                              hipStream_t stream) {
    const float* Gu = (const float*)d_in[0];
    const float* Gi = (const float*)d_in[1];
    const int* eh = (const int*)d_in[2];
    const int* et = (const int*)d_in[3];
    float* out = (float*)d_out;

    char* p = (char*)d_ws;
    __half* s4       = (__half*)p;     p += (size_t)EE * 4 * 2;       // 6.4 MB
    int*    csr_tail = (int*)p;        p += (size_t)EE * 4;           // 3.2 MB
    int*    csr_head = (int*)p;        p += (size_t)EE * 4;           // 3.2 MB
    int*    rank     = (int*)p;        p += (size_t)EE * 4;           // 3.2 MB (fallback only)
    int*    offsets  = (int*)p;        p += ((size_t)(NN + 1) * 4 + 15) / 16 * 16;
    int*    deg0     = (int*)p;        p += (size_t)NN * 4;
    int*    bsum     = (int*)p;        p += ((size_t)SCAN_B * 4 + 15) / 16 * 16;
    float*  dcol1    = (float*)p;      p += (size_t)NN * 4 * 4;
    __half* Ytab     = (__half*)p;     p += (size_t)(NN + 1) * 64 * 2; // 7.68 MB
    __half* Ttab     = (__half*)p;     p += (size_t)(NN + 1) * 64 * 2; // 7.68 MB
    __half* ZN       = (__half*)p;     // NN*64*2 = 7.68 MB -> total ~44 MB
    __half* Y1i      = Ytab;           // aliases Ytab (dead after zacc phase)

    void* args[] = { (void*)&eh, (void*)&et, (void*)&Gu, (void*)&Gi,
                     (void*)&deg0, (void*)&offsets, (void*)&bsum,
                     (void*)&csr_tail, (void*)&csr_head,
                     (void*)&Ytab, (void*)&Ttab, (void*)&ZN, (void*)&s4,
                     (void*)&dcol1, (void*)&out };
    hipError_t cerr = hipLaunchCooperativeKernel((void*)mega, dim3(GRID), dim3(256),
                                                 args, 0, stream);
    if (cerr != hipSuccess) {
        // fallback: R21 9-dispatch path
        hipMemsetAsync(deg0, 0, NN * sizeof(int), stream);
        edge_count<<<EV_B, 256, 0, stream>>>(eh, deg0, rank);
        scan_local<<<SCAN_B, 256, 0, stream>>>(deg0, offsets, bsum);
        scan_add2<<<SCAN_B, 256, 0, stream>>>(offsets, bsum);
        scatter_prep<<<EV_B + NW1_B, 256, 0, stream>>>(eh, et, rank, offsets, csr_tail,
                                                       Gu, Gi, deg0, Ytab, Ttab);
        zacc<<<N8_B, 256, 0, stream>>>(offsets, csr_tail, Ytab, ZN, csr_head);
        attdot_sm<<<(EE + 255) / 256, 256, 0, stream>>>(csr_head, csr_tail, ZN, Ttab, s4);
        deg_y1<<<NW_B, 256, 0, stream>>>(offsets, s4, dcol1, Gu, Gi, Y1i);
        outk<<<N8_B, 256, 0, stream>>>(offsets, csr_tail, Y1i, s4, dcol1, Gu, Gi, out);
    }
}

// Round 9
// 255.466 us; speedup vs baseline: 4.5912x; 4.5912x over previous
//
#include <hip/hip_runtime.h>
#include <hip/hip_fp16.h>

// DGCF single-layer, 2 routing iters (MI355X). fp32 in / fp32 out.
// R23 = R21 revert + deeper gather pipelining.
// R22 post-mortem (mega coop kernel, 1127us steady, FETCH 231MB vs 54MB):
// grid.sync() must flush/invalidate the 8 non-coherent per-XCD L2s at
// every barrier -> each phase refetches tables from LLC/HBM; dispatch
// boundaries were the CHEAP coherence mechanism, not the cost. Reverted.
// Tweaks on top of R21 (only scheduling, no arithmetic change):
//  - zacc/outk: unroll 8 (was 4) -> 8 full-line gathers in flight/wave
//    (bucket avg deg 13.3, so one unrolled step covers most buckets).
//  - attdot_sm: 2 edges per lane (independent chains, 2x ILP, half the
//    waves).
// Unchanged from R21 (passing, 252.7us): rank-from-count atomic-free
// scatter, tail-only 4B scatter, zacc 2-node x 32-lane + coalesced head
// fill, per-edge fused softmax, deg_y1, single-visit outk over Y1i[n][64].

#define NUSERS 30000
#define NN     60000
#define EE     800000
#define SCAN_B ((NN + 255) / 256)       // 235 scan blocks
#define EV_B   ((EE / 4 + 255) / 256)   // 782 int4 edge blocks
#define NW1_B  ((NN + 1 + 3) / 4)       // 15001 node blocks (incl zero row)
#define N8_B   ((NN + 7) / 8)           // 7500 blocks (8 nodes per block)

__device__ __forceinline__ float getX(const float* __restrict__ Gu,
                                      const float* __restrict__ Gi,
                                      int n, int c) {
    return (n < NUSERS) ? Gu[n * 64 + c] : Gi[(n - NUSERS) * 64 + c];
}

__device__ __forceinline__ int clampN(int n) {
    return ((unsigned)n < (unsigned)NN) ? n : 0;
}

__device__ __forceinline__ __half2 bch2(float f) {
    return __builtin_bit_cast(__half2, f);
}

// ---- CSR build ----

// Count degrees AND record each edge's rank within its head bucket
// (atomicAdd return value). rank written coalesced (int4).
__global__ void edge_count(const int* __restrict__ eh, int* __restrict__ deg0,
                           int* __restrict__ rank) {
    int e4 = (blockIdx.x * blockDim.x + threadIdx.x) * 4;
    if (e4 >= EE) return;
    int4 h = *(const int4*)(eh + e4);
    int4 r;
    r.x = atomicAdd(&deg0[clampN(h.x)], 1);
    r.y = atomicAdd(&deg0[clampN(h.y)], 1);
    r.z = atomicAdd(&deg0[clampN(h.z)], 1);
    r.w = atomicAdd(&deg0[clampN(h.w)], 1);
    *(int4*)(rank + e4) = r;
}

// In-block exclusive scan of 256 ints.
__global__ void scan_local(const int* __restrict__ deg0, int* __restrict__ offsets,
                           int* __restrict__ bsum) {
    int gid = blockIdx.x * 256 + threadIdx.x;
    int lane = threadIdx.x & 63, w = threadIdx.x >> 6;
    int vdeg = (gid < NN) ? deg0[gid] : 0;
    int x = vdeg;
    #pragma unroll
    for (int d = 1; d < 64; d <<= 1) {
        int y = __shfl_up(x, d, 64);
        if (lane >= d) x += y;
    }
    __shared__ int wsum[4];
    if (lane == 63) wsum[w] = x;
    __syncthreads();
    int wpre = 0;
    #pragma unroll
    for (int j = 0; j < 4; ++j) wpre += (j < w) ? wsum[j] : 0;
    int incl = x + wpre;
    if (gid < NN) offsets[gid] = incl - vdeg;
    if (threadIdx.x == 255) bsum[blockIdx.x] = incl;
}

// Each block re-scans the 235 block sums (cheap) and adds its own prefix.
__global__ void scan_add2(int* __restrict__ offsets, const int* __restrict__ bsum) {
    int tid = threadIdx.x, lane = tid & 63, w = tid >> 6;
    int vv = (tid < SCAN_B) ? bsum[tid] : 0;
    int x = vv;
    #pragma unroll
    for (int d = 1; d < 64; d <<= 1) {
        int y = __shfl_up(x, d, 64);
        if (lane >= d) x += y;
    }
    __shared__ int wsum[4];
    __shared__ int bpre;
    if (lane == 63) wsum[w] = x;
    __syncthreads();
    int wpre = 0;
    #pragma unroll
    for (int j = 0; j < 4; ++j) wpre += (j < w) ? wsum[j] : 0;
    if (tid == blockIdx.x) bpre = x + wpre - vv;   // exclusive prefix of this block
    __syncthreads();
    int gid = blockIdx.x * 256 + tid;
    if (gid < NN) offsets[gid] += bpre;
    if (gid == 0) offsets[NN] = EE;
}

// ---- merged dispatch: edge_scatter (blocks [0,EV_B)) || prep0s (rest) ----
// scatter: atomic-free permute; ONE scattered 4B (tail) store per edge.
// prep0s: node-interleaved Ytab/Ttab rows (64 halfs = all intents), zero
// row at n == NN.
__global__ void scatter_prep(const int* __restrict__ eh, const int* __restrict__ et,
                             const int* __restrict__ rank,
                             const int* __restrict__ offsets,
                             int* __restrict__ csr_tail,
                             const float* __restrict__ Gu, const float* __restrict__ Gi,
                             const int* __restrict__ deg0,
                             __half* __restrict__ Ytab, __half* __restrict__ Ttab) {
    if (blockIdx.x < EV_B) {
        int e4 = (blockIdx.x * 256 + threadIdx.x) * 4;
        if (e4 >= EE) return;
        int4 h = *(const int4*)(eh + e4);
        int4 t = *(const int4*)(et + e4);
        int4 r = *(const int4*)(rank + e4);
        int s0 = offsets[clampN(h.x)] + r.x;
        if ((unsigned)s0 < EE) csr_tail[s0] = clampN(t.x);
        int s1 = offsets[clampN(h.y)] + r.y;
        if ((unsigned)s1 < EE) csr_tail[s1] = clampN(t.y);
        int s2 = offsets[clampN(h.z)] + r.z;
        if ((unsigned)s2 < EE) csr_tail[s2] = clampN(t.z);
        int s3 = offsets[clampN(h.w)] + r.w;
        if ((unsigned)s3 < EE) csr_tail[s3] = clampN(t.w);
    } else {
        int n = (blockIdx.x - EV_B) * 4 + (threadIdx.x >> 6);
        if (n > NN) return;
        int lane = threadIdx.x & 63;            // lane == channel c
        float x = (n < NN) ? getX(Gu, Gi, n, lane) : 0.f;
        float sx = x * x;
        #pragma unroll
        for (int m = 1; m < 16; m <<= 1) sx += __shfl_xor(sx, m, 64);  // 16-ch intent group
        float invx = rsqrtf(fmaxf(sx, 1e-12f));
        float d0 = rsqrtf(fmaxf(0.25f * (float)((n < NN) ? deg0[n] : 1), 1e-30f));
        size_t a = (size_t)n * 64 + lane;
        Ytab[a] = __float2half(d0 * x);          // iter-0 Y (scores==0.25 folded)
        Ttab[a] = __float2half(tanhf(x * invx)); // tanh of l2norm(x) per intent
    }
}

// ---- zacc: Z1 accumulate + per-intent l2norm -> ZN[n][64] ----
// wave = 2 nodes x 32 half2-ch lanes; unroll-8 -> 8 full-line gathers in
// flight per wave. Also fills csr_head coalesced (heads are CSR-sorted).
__global__ void zacc(const int* __restrict__ offsets, const int* __restrict__ csr_tail,
                     const __half* __restrict__ Ytab, __half* __restrict__ ZN,
                     int* __restrict__ csr_head) {
    int tid = threadIdx.x;
    int n = blockIdx.x * 8 + (tid >> 5);
    if (n >= NN) return;
    int cc = tid & 31;                           // half2-channel (2cc, 2cc+1)
    int s0 = offsets[n], s1 = offsets[n + 1];
    for (int k = s0 + cc; k < s1; k += 32) csr_head[k] = n;  // coalesced head fill
    float accx = 0.f, accy = 0.f;
    for (int base = s0; base < s1; base += 8) {
        #pragma unroll
        for (int u = 0; u < 8; ++u) {
            int kk = base + u;
            bool act = kk < s1;
            int kc = act ? kk : s0;              // in-bounds; deg >= 1 always
            int t = act ? csr_tail[kc] : NN;     // NN = zero row
            __half2 y = *(const __half2*)(Ytab + (size_t)t * 64 + cc * 2);
            float2 yf = __half22float2(y);
            accx += yf.x; accy += yf.y;
        }
    }
    // per-intent l2 norm: 8-lane group = 16 channels = 1 intent
    float ss = accx * accx + accy * accy;
    ss += __shfl_xor(ss, 1, 64);
    ss += __shfl_xor(ss, 2, 64);
    ss += __shfl_xor(ss, 4, 64);
    float inv = rsqrtf(fmaxf(ss, 1e-12f));
    *(__half2*)(ZN + (size_t)n * 64 + cc * 2) =
        __floats2half2_rn(accx * inv, accy * inv);
}

// ---- attdot_sm: per-edge dots + per-edge softmax over intents ----
// 2 edges per lane (independent chains, 2x ILP). No cross-lane ops.
// softmax(A)=softmax(dot) since A = 1 + dot (shift-invariant).
__device__ __forceinline__ void attdot_one(int k,
        const int* __restrict__ csr_head, const int* __restrict__ csr_tail,
        const __half* __restrict__ ZN, const __half* __restrict__ Ttab,
        __half* __restrict__ s4) {
    int h = csr_head[k], t = csr_tail[k];
    const float4* zp = (const float4*)(ZN + (size_t)h * 64);
    const float4* tp = (const float4*)(Ttab + (size_t)t * 64);
    float dot[4];
    #pragma unroll
    for (int i = 0; i < 4; ++i) {
        float4 za = zp[2 * i], zb = zp[2 * i + 1];
        float4 ta = tp[2 * i], tb = tp[2 * i + 1];
        __half2 acc = __floats2half2_rn(0.f, 0.f);
        acc = __hfma2(bch2(za.x), bch2(ta.x), acc);
        acc = __hfma2(bch2(za.y), bch2(ta.y), acc);
        acc = __hfma2(bch2(za.z), bch2(ta.z), acc);
        acc = __hfma2(bch2(za.w), bch2(ta.w), acc);
        acc = __hfma2(bch2(zb.x), bch2(tb.x), acc);
        acc = __hfma2(bch2(zb.y), bch2(tb.y), acc);
        acc = __hfma2(bch2(zb.z), bch2(tb.z), acc);
        acc = __hfma2(bch2(zb.w), bch2(tb.w), acc);
        float2 f = __half22float2(acc);
        dot[i] = f.x + f.y;
    }
    float mx = fmaxf(fmaxf(dot[0], dot[1]), fmaxf(dot[2], dot[3]));
    float e0 = __expf(dot[0] - mx), e1 = __expf(dot[1] - mx);
    float e2 = __expf(dot[2] - mx), e3 = __expf(dot[3] - mx);
    float inv = 1.f / (e0 + e1 + e2 + e3);
    __half2 q01 = __floats2half2_rn(e0 * inv, e1 * inv);
    __half2 q23 = __floats2half2_rn(e2 * inv, e3 * inv);
    int2 st;
    st.x = __builtin_bit_cast(int, q01);
    st.y = __builtin_bit_cast(int, q23);
    *(int2*)(s4 + (size_t)k * 4) = st;
}

__global__ void attdot_sm(const int* __restrict__ csr_head, const int* __restrict__ csr_tail,
                          const __half* __restrict__ ZN, const __half* __restrict__ Ttab,
                          __half* __restrict__ s4) {
    int k = blockIdx.x * 512 + threadIdx.x;
    if (k < EE) attdot_one(k, csr_head, csr_tail, ZN, Ttab, s4);
    int k2 = k + 256;
    if (k2 < EE) attdot_one(k2, csr_head, csr_tail, ZN, Ttab, s4);
}

// ---- deg_y1: bucket-sum of s4 -> dcol1 + Y1i row (wave per node) ----
// Pure loads + adds (softmax already done edge-parallel).
__global__ void deg_y1(const int* __restrict__ offsets, const __half* __restrict__ s4,
                       float* __restrict__ dcol1,
                       const float* __restrict__ Gu, const float* __restrict__ Gi,
                       __half* __restrict__ Y1i) {
    int n = blockIdx.x * 4 + (threadIdx.x >> 6);
    if (n >= NN) return;
    int lane = threadIdx.x & 63;
    int s0 = offsets[n], s1 = offsets[n + 1];
    float sum0 = 0.f, sum1 = 0.f, sum2 = 0.f, sum3 = 0.f;
    for (int k = s0 + lane; k < s1; k += 64) {
        int2 raw = *(const int2*)(s4 + (size_t)k * 4);
        float2 fa = __half22float2(__builtin_bit_cast(__half2, raw.x));
        float2 fb = __half22float2(__builtin_bit_cast(__half2, raw.y));
        sum0 += fa.x; sum1 += fa.y; sum2 += fb.x; sum3 += fb.y;
    }
    #pragma unroll
    for (int m = 1; m < 64; m <<= 1) {
        sum0 += __shfl_xor(sum0, m, 64);
        sum1 += __shfl_xor(sum1, m, 64);
        sum2 += __shfl_xor(sum2, m, 64);
        sum3 += __shfl_xor(sum3, m, 64);
    }
    int i = lane >> 4;                           // intent of channel 'lane'
    float dsel = (i == 0) ? sum0 : (i == 1) ? sum1 : (i == 2) ? sum2 : sum3;
    float d = rsqrtf(fmaxf(dsel, 1e-30f));
    if (lane < 4) {
        float ds = (lane == 0) ? sum0 : (lane == 1) ? sum1 : (lane == 2) ? sum2 : sum3;
        dcol1[n * 4 + lane] = rsqrtf(fmaxf(ds, 1e-30f));
    }
    float x = getX(Gu, Gi, n, lane);
    Y1i[(size_t)n * 64 + lane] = __float2half(d * x);
}

// ---- output pass: Z2 gather + finalize ----
// wave = 2 nodes x 32 half2-ch lanes (all 4 intents at once). Per edge:
// broadcast csr_tail + s4 (lane extracts its intent's half), 32 lanes
// gather one full 128B Y1i row. Unroll-8. Single visit per edge.
__global__ void outk(const int* __restrict__ offsets, const int* __restrict__ csr_tail,
                     const __half* __restrict__ Y1i, const __half* __restrict__ s4,
                     const float* __restrict__ dcol1,
                     const float* __restrict__ Gu, const float* __restrict__ Gi,
                     float* __restrict__ out) {
    int tid = threadIdx.x;
    int n = blockIdx.x * 8 + (tid >> 5);
    if (n >= NN) return;
    int cc = tid & 31;                           // half2-channel (2cc, 2cc+1)
    int s0 = offsets[n], s1 = offsets[n + 1];
    float accx = 0.f, accy = 0.f;
    for (int base = s0; base < s1; base += 8) {
        #pragma unroll
        for (int u = 0; u < 8; ++u) {
            int kk = base + u;
            bool act = kk < s1;
            int kc = act ? kk : s0;              // in-bounds; deg >= 1 always
            int t = csr_tail[kc];
            int2 raw = *(const int2*)(s4 + (size_t)kc * 4);
            int word = (cc & 16) ? raw.y : raw.x;
            unsigned short us = (unsigned short)(word >> ((cc & 8) ? 16 : 0));
            float s = act ? __half2float(__builtin_bit_cast(__half, us)) : 0.f;
            __half2 y = *(const __half2*)(Y1i + (size_t)t * 64 + cc * 2);
            float2 yf = __half22float2(y);
            accx = fmaf(s, yf.x, accx);
            accy = fmaf(s, yf.y, accy);
        }
    }
    float d = dcol1[n * 4 + (cc >> 3)];
    int ch = cc * 2;
    const float* xr = (n < NUSERS) ? (Gu + (size_t)n * 64 + ch)
                                   : (Gi + (size_t)(n - NUSERS) * 64 + ch);
    float2 x2 = *(const float2*)xr;
    float2 o;
    o.x = 0.5f * (x2.x + d * accx);
    o.y = 0.5f * (x2.y + d * accy);
    *(float2*)(out + (size_t)n * 64 + ch) = o;
}

// ---- launch ----

extern "C" void kernel_launch(void* const* d_in, const int* in_sizes, int n_in,
                              void* d_out, int out_size, void* d_ws, size_t ws_size,
                              hipStream_t stream) {
    const float* Gu = (const float*)d_in[0];
    const float* Gi = (const float*)d_in[1];
    const int* eh = (const int*)d_in[2];
    const int* et = (const int*)d_in[3];
    float* out = (float*)d_out;

    char* p = (char*)d_ws;
    __half* s4       = (__half*)p;     p += (size_t)EE * 4 * 2;       // 6.4 MB
    int*    csr_tail = (int*)p;        p += (size_t)EE * 4;           // 3.2 MB
    int*    csr_head = (int*)p;        p += (size_t)EE * 4;           // 3.2 MB
    int*    rank     = (int*)p;        p += (size_t)EE * 4;           // 3.2 MB
    int*    offsets  = (int*)p;        p += ((size_t)(NN + 1) * 4 + 15) / 16 * 16;
    int*    deg0     = (int*)p;        p += (size_t)NN * 4;
    int*    bsum     = (int*)p;        p += ((size_t)SCAN_B * 4 + 15) / 16 * 16;
    float*  dcol1    = (float*)p;      p += (size_t)NN * 4 * 4;
    __half* Ytab     = (__half*)p;     p += (size_t)(NN + 1) * 64 * 2; // 7.68 MB
    __half* Ttab     = (__half*)p;     p += (size_t)(NN + 1) * 64 * 2; // 7.68 MB
    __half* ZN       = (__half*)p;     // NN*64*2 = 7.68 MB -> total ~41 MB
    __half* Y1i      = Ytab;           // aliases Ytab (dead after zacc)

    const int nw_blocks = (NN + 3) / 4;

    // CSR build (rank-from-count: no cursor, no scatter atomics)
    hipMemsetAsync(deg0, 0, NN * sizeof(int), stream);
    edge_count<<<EV_B, 256, 0, stream>>>(eh, deg0, rank);
    scan_local<<<SCAN_B, 256, 0, stream>>>(deg0, offsets, bsum);
    scan_add2<<<SCAN_B, 256, 0, stream>>>(offsets, bsum);

    // atomic-free edge permute (tail-only 4B scatter) || prep tables
    scatter_prep<<<EV_B + NW1_B, 256, 0, stream>>>(eh, et, rank, offsets, csr_tail,
                                                   Gu, Gi, deg0, Ytab, Ttab);

    // iter 0: Z1 accumulate + norm + head fill, then per-edge dots+softmax
    zacc<<<N8_B, 256, 0, stream>>>(offsets, csr_tail, Ytab, ZN, csr_head);
    attdot_sm<<<(EE + 511) / 512, 256, 0, stream>>>(csr_head, csr_tail, ZN, Ttab, s4);

    // bucket sums -> dcol1 + Y1i rows
    deg_y1<<<nw_blocks, 256, 0, stream>>>(offsets, s4, dcol1, Gu, Gi, Y1i);

    // iter 1 propagate + finalize: single visit per edge, full-line gathers
    outk<<<N8_B, 256, 0, stream>>>(offsets, csr_tail, Y1i, s4, dcol1, Gu, Gi, out);
}

// Round 10
// 237.161 us; speedup vs baseline: 4.9456x; 1.0772x over previous
//
#include <hip/hip_runtime.h>
#include <hip/hip_fp16.h>

// DGCF single-layer, 2 routing iters (MI355X). fp32 in / fp32 out.
// R24: fuse zacc + attdot_sm + deg_y1 into one block-local kernel (zat).
// R23 post-mortem: deeper unroll neutral -> kernels not latency-limited
// internally; residual cost = pass count + inter-kernel round-trips.
// Key insight: a block's per-edge dots only need the ZN rows of its OWN
// 8 head nodes (just computed in phase A) -> keep them in LDS; no grid
// coherence needed (the R22 coop disaster is avoided).
//  - phase A: zacc into LDS zn[8][72] (pad kills stride-128 bank confl).
//    Global ZN deleted.
//  - phase B: 256 threads stride block's edge span; head-local via 8-way
//    compare vs LDS offsets -> csr_head DELETED (no fill/write/read).
//    Per edge: Ttab[t] row gather, LDS zn row, 4 dots, in-lane softmax,
//    s4 store, LDS-atomic-add scores to per-node sums.
//  - phase C: dcol1 + Y1i rows from LDS sums (deg_y1 deleted; s4 re-read
//    deleted). Y1i now occupies the freed ZN buffer (must NOT alias Ytab:
//    other blocks still read Ytab while we write Y1i).
// 9 -> 7 dispatches. outk/scatter/scans: R21 verified form (R23 unroll-8
// reverted, measured neutral).

#define NUSERS 30000
#define NN     60000
#define EE     800000
#define SCAN_B ((NN + 255) / 256)       // 235 scan blocks
#define EV_B   ((EE / 4 + 255) / 256)   // 782 int4 edge blocks
#define NW1_B  ((NN + 1 + 3) / 4)       // 15001 node blocks (incl zero row)
#define N8_B   (NN / 8)                 // 7500 blocks (8 nodes; 8 | NN)

__device__ __forceinline__ float getX(const float* __restrict__ Gu,
                                      const float* __restrict__ Gi,
                                      int n, int c) {
    return (n < NUSERS) ? Gu[n * 64 + c] : Gi[(n - NUSERS) * 64 + c];
}

__device__ __forceinline__ int clampN(int n) {
    return ((unsigned)n < (unsigned)NN) ? n : 0;
}

__device__ __forceinline__ __half2 bch2(float f) {
    return __builtin_bit_cast(__half2, f);
}

// ---- CSR build ----

// Count degrees AND record each edge's rank within its head bucket
// (atomicAdd return value). rank written coalesced (int4).
__global__ void edge_count(const int* __restrict__ eh, int* __restrict__ deg0,
                           int* __restrict__ rank) {
    int e4 = (blockIdx.x * blockDim.x + threadIdx.x) * 4;
    if (e4 >= EE) return;
    int4 h = *(const int4*)(eh + e4);
    int4 r;
    r.x = atomicAdd(&deg0[clampN(h.x)], 1);
    r.y = atomicAdd(&deg0[clampN(h.y)], 1);
    r.z = atomicAdd(&deg0[clampN(h.z)], 1);
    r.w = atomicAdd(&deg0[clampN(h.w)], 1);
    *(int4*)(rank + e4) = r;
}

// In-block exclusive scan of 256 ints.
__global__ void scan_local(const int* __restrict__ deg0, int* __restrict__ offsets,
                           int* __restrict__ bsum) {
    int gid = blockIdx.x * 256 + threadIdx.x;
    int lane = threadIdx.x & 63, w = threadIdx.x >> 6;
    int vdeg = (gid < NN) ? deg0[gid] : 0;
    int x = vdeg;
    #pragma unroll
    for (int d = 1; d < 64; d <<= 1) {
        int y = __shfl_up(x, d, 64);
        if (lane >= d) x += y;
    }
    __shared__ int wsum[4];
    if (lane == 63) wsum[w] = x;
    __syncthreads();
    int wpre = 0;
    #pragma unroll
    for (int j = 0; j < 4; ++j) wpre += (j < w) ? wsum[j] : 0;
    int incl = x + wpre;
    if (gid < NN) offsets[gid] = incl - vdeg;
    if (threadIdx.x == 255) bsum[blockIdx.x] = incl;
}

// Each block re-scans the 235 block sums (cheap) and adds its own prefix.
__global__ void scan_add2(int* __restrict__ offsets, const int* __restrict__ bsum) {
    int tid = threadIdx.x, lane = tid & 63, w = tid >> 6;
    int vv = (tid < SCAN_B) ? bsum[tid] : 0;
    int x = vv;
    #pragma unroll
    for (int d = 1; d < 64; d <<= 1) {
        int y = __shfl_up(x, d, 64);
        if (lane >= d) x += y;
    }
    __shared__ int wsum[4];
    __shared__ int bpre;
    if (lane == 63) wsum[w] = x;
    __syncthreads();
    int wpre = 0;
    #pragma unroll
    for (int j = 0; j < 4; ++j) wpre += (j < w) ? wsum[j] : 0;
    if (tid == blockIdx.x) bpre = x + wpre - vv;   // exclusive prefix of this block
    __syncthreads();
    int gid = blockIdx.x * 256 + tid;
    if (gid < NN) offsets[gid] += bpre;
    if (gid == 0) offsets[NN] = EE;
}

// ---- merged dispatch: edge_scatter (blocks [0,EV_B)) || prep0s (rest) ----
// scatter: atomic-free permute; ONE scattered 4B (tail) store per edge.
// prep0s: node-interleaved Ytab/Ttab rows (64 halfs = all intents), zero
// row at n == NN.
__global__ void scatter_prep(const int* __restrict__ eh, const int* __restrict__ et,
                             const int* __restrict__ rank,
                             const int* __restrict__ offsets,
                             int* __restrict__ csr_tail,
                             const float* __restrict__ Gu, const float* __restrict__ Gi,
                             const int* __restrict__ deg0,
                             __half* __restrict__ Ytab, __half* __restrict__ Ttab) {
    if (blockIdx.x < EV_B) {
        int e4 = (blockIdx.x * 256 + threadIdx.x) * 4;
        if (e4 >= EE) return;
        int4 h = *(const int4*)(eh + e4);
        int4 t = *(const int4*)(et + e4);
        int4 r = *(const int4*)(rank + e4);
        int s0 = offsets[clampN(h.x)] + r.x;
        if ((unsigned)s0 < EE) csr_tail[s0] = clampN(t.x);
        int s1 = offsets[clampN(h.y)] + r.y;
        if ((unsigned)s1 < EE) csr_tail[s1] = clampN(t.y);
        int s2 = offsets[clampN(h.z)] + r.z;
        if ((unsigned)s2 < EE) csr_tail[s2] = clampN(t.z);
        int s3 = offsets[clampN(h.w)] + r.w;
        if ((unsigned)s3 < EE) csr_tail[s3] = clampN(t.w);
    } else {
        int n = (blockIdx.x - EV_B) * 4 + (threadIdx.x >> 6);
        if (n > NN) return;
        int lane = threadIdx.x & 63;            // lane == channel c
        float x = (n < NN) ? getX(Gu, Gi, n, lane) : 0.f;
        float sx = x * x;
        #pragma unroll
        for (int m = 1; m < 16; m <<= 1) sx += __shfl_xor(sx, m, 64);  // 16-ch intent group
        float invx = rsqrtf(fmaxf(sx, 1e-12f));
        float d0 = rsqrtf(fmaxf(0.25f * (float)((n < NN) ? deg0[n] : 1), 1e-30f));
        size_t a = (size_t)n * 64 + lane;
        Ytab[a] = __float2half(d0 * x);          // iter-0 Y (scores==0.25 folded)
        Ttab[a] = __float2half(tanhf(x * invx)); // tanh of l2norm(x) per intent
    }
}

// ---- zat: fused zacc + attdot_sm + deg_y1 (block = 8 nodes) ----
__global__ void zat(const int* __restrict__ offsets, const int* __restrict__ csr_tail,
                    const __half* __restrict__ Ytab, const __half* __restrict__ Ttab,
                    __half* __restrict__ s4, float* __restrict__ dcol1,
                    const float* __restrict__ Gu, const float* __restrict__ Gi,
                    __half* __restrict__ Y1i) {
    __shared__ __half zn[8][72];        // 144B row stride (+16B pad: no bank confl)
    __shared__ float ssum[8][4];        // per-node per-intent score sums
    __shared__ int soff[9];
    int tid = threadIdx.x;
    int n0 = blockIdx.x * 8;            // 8 | NN, always full
    if (tid < 9) soff[tid] = offsets[n0 + tid];
    if (tid >= 32 && tid < 64) ssum[(tid - 32) >> 2][tid & 3] = 0.f;
    __syncthreads();

    // phase A: per 32-lane group, accumulate Z for node n0+g, norm -> LDS
    {
        int g = tid >> 5, cc = tid & 31;
        int s0 = soff[g], s1 = soff[g + 1];
        float accx = 0.f, accy = 0.f;
        for (int base = s0; base < s1; base += 4) {
            #pragma unroll
            for (int u = 0; u < 4; ++u) {
                int kk = base + u;
                bool act = kk < s1;
                int kc = act ? kk : s0;          // in-bounds; deg >= 1 always
                int t = act ? csr_tail[kc] : NN; // NN = zero row
                __half2 y = *(const __half2*)(Ytab + (size_t)t * 64 + cc * 2);
                float2 yf = __half22float2(y);
                accx += yf.x; accy += yf.y;
            }
        }
        float ss = accx * accx + accy * accy;
        ss += __shfl_xor(ss, 1, 64);
        ss += __shfl_xor(ss, 2, 64);
        ss += __shfl_xor(ss, 4, 64);             // 8-lane group = 1 intent
        float inv = rsqrtf(fmaxf(ss, 1e-12f));
        *(__half2*)&zn[g][cc * 2] = __floats2half2_rn(accx * inv, accy * inv);
    }
    __syncthreads();

    // phase B: per-edge dots + softmax over the block's edge span
    int e0 = soff[0], e1 = soff[8];
    for (int k = e0 + tid; k < e1; k += 256) {
        int hl = 0;
        #pragma unroll
        for (int j = 1; j < 8; ++j) hl += (k >= soff[j]) ? 1 : 0;
        int t = csr_tail[k];
        const float4* tp = (const float4*)(Ttab + (size_t)t * 64);
        float dot[4];
        #pragma unroll
        for (int i = 0; i < 4; ++i) {
            float4 za = *(const float4*)&zn[hl][i * 16];
            float4 zb = *(const float4*)&zn[hl][i * 16 + 8];
            float4 ta = tp[2 * i], tb = tp[2 * i + 1];
            __half2 acc = __floats2half2_rn(0.f, 0.f);
            acc = __hfma2(bch2(za.x), bch2(ta.x), acc);
            acc = __hfma2(bch2(za.y), bch2(ta.y), acc);
            acc = __hfma2(bch2(za.z), bch2(ta.z), acc);
            acc = __hfma2(bch2(za.w), bch2(ta.w), acc);
            acc = __hfma2(bch2(zb.x), bch2(tb.x), acc);
            acc = __hfma2(bch2(zb.y), bch2(tb.y), acc);
            acc = __hfma2(bch2(zb.z), bch2(tb.z), acc);
            acc = __hfma2(bch2(zb.w), bch2(tb.w), acc);
            float2 f = __half22float2(acc);
            dot[i] = f.x + f.y;
        }
        float mx = fmaxf(fmaxf(dot[0], dot[1]), fmaxf(dot[2], dot[3]));
        float q0 = __expf(dot[0] - mx), q1 = __expf(dot[1] - mx);
        float q2 = __expf(dot[2] - mx), q3 = __expf(dot[3] - mx);
        float inv = 1.f / (q0 + q1 + q2 + q3);
        q0 *= inv; q1 *= inv; q2 *= inv; q3 *= inv;
        __half2 o01 = __floats2half2_rn(q0, q1);
        __half2 o23 = __floats2half2_rn(q2, q3);
        int2 st;
        st.x = __builtin_bit_cast(int, o01);
        st.y = __builtin_bit_cast(int, o23);
        *(int2*)(s4 + (size_t)k * 4) = st;
        atomicAdd(&ssum[hl][0], q0);
        atomicAdd(&ssum[hl][1], q1);
        atomicAdd(&ssum[hl][2], q2);
        atomicAdd(&ssum[hl][3], q3);
    }
    __syncthreads();

    // phase C: dcol1 + Y1i rows from LDS sums
    if (tid < 32) {
        int nn = n0 + (tid >> 2);
        dcol1[nn * 4 + (tid & 3)] = rsqrtf(fmaxf(ssum[tid >> 2][tid & 3], 1e-30f));
    }
    #pragma unroll
    for (int v = tid; v < 512; v += 256) {
        int nn = n0 + (v >> 6);
        int ch = v & 63;
        float d = rsqrtf(fmaxf(ssum[v >> 6][ch >> 4], 1e-30f));
        float x = getX(Gu, Gi, nn, ch);
        Y1i[(size_t)nn * 64 + ch] = __float2half(d * x);
    }
}

// ---- output pass: Z2 gather + finalize (R21 verified) ----
// wave = 2 nodes x 32 half2-ch lanes (all 4 intents at once). Per edge:
// broadcast csr_tail + s4 (lane extracts its intent's half), 32 lanes
// gather one full 128B Y1i row. Single visit per edge. float2 store.
__global__ void outk(const int* __restrict__ offsets, const int* __restrict__ csr_tail,
                     const __half* __restrict__ Y1i, const __half* __restrict__ s4,
                     const float* __restrict__ dcol1,
                     const float* __restrict__ Gu, const float* __restrict__ Gi,
                     float* __restrict__ out) {
    int tid = threadIdx.x;
    int n = blockIdx.x * 8 + (tid >> 5);
    if (n >= NN) return;
    int cc = tid & 31;                           // half2-channel (2cc, 2cc+1)
    int s0 = offsets[n], s1 = offsets[n + 1];
    float accx = 0.f, accy = 0.f;
    for (int base = s0; base < s1; base += 4) {
        #pragma unroll
        for (int u = 0; u < 4; ++u) {
            int kk = base + u;
            bool act = kk < s1;
            int kc = act ? kk : s0;              // in-bounds; deg >= 1 always
            int t = csr_tail[kc];
            int2 raw = *(const int2*)(s4 + (size_t)kc * 4);
            int word = (cc & 16) ? raw.y : raw.x;
            unsigned short us = (unsigned short)(word >> ((cc & 8) ? 16 : 0));
            float s = act ? __half2float(__builtin_bit_cast(__half, us)) : 0.f;
            __half2 y = *(const __half2*)(Y1i + (size_t)t * 64 + cc * 2);
            float2 yf = __half22float2(y);
            accx = fmaf(s, yf.x, accx);
            accy = fmaf(s, yf.y, accy);
        }
    }
    float d = dcol1[n * 4 + (cc >> 3)];
    int ch = cc * 2;
    const float* xr = (n < NUSERS) ? (Gu + (size_t)n * 64 + ch)
                                   : (Gi + (size_t)(n - NUSERS) * 64 + ch);
    float2 x2 = *(const float2*)xr;
    float2 o;
    o.x = 0.5f * (x2.x + d * accx);
    o.y = 0.5f * (x2.y + d * accy);
    *(float2*)(out + (size_t)n * 64 + ch) = o;
}

// ---- launch ----

extern "C" void kernel_launch(void* const* d_in, const int* in_sizes, int n_in,
                              void* d_out, int out_size, void* d_ws, size_t ws_size,
                              hipStream_t stream) {
    const float* Gu = (const float*)d_in[0];
    const float* Gi = (const float*)d_in[1];
    const int* eh = (const int*)d_in[2];
    const int* et = (const int*)d_in[3];
    float* out = (float*)d_out;

    char* p = (char*)d_ws;
    __half* s4       = (__half*)p;     p += (size_t)EE * 4 * 2;       // 6.4 MB
    int*    csr_tail = (int*)p;        p += (size_t)EE * 4;           // 3.2 MB
    int*    rank     = (int*)p;        p += (size_t)EE * 4;           // 3.2 MB
    int*    offsets  = (int*)p;        p += ((size_t)(NN + 1) * 4 + 15) / 16 * 16;
    int*    deg0     = (int*)p;        p += (size_t)NN * 4;
    int*    bsum     = (int*)p;        p += ((size_t)SCAN_B * 4 + 15) / 16 * 16;
    float*  dcol1    = (float*)p;      p += (size_t)NN * 4 * 4;
    __half* Ytab     = (__half*)p;     p += (size_t)(NN + 1) * 64 * 2; // 7.68 MB
    __half* Ttab     = (__half*)p;     p += (size_t)(NN + 1) * 64 * 2; // 7.68 MB
    __half* Y1i      = (__half*)p;     // NN*64*2 = 7.68 MB (former ZN slot;
                                       // must NOT alias Ytab: zat writes Y1i
                                       // while other blocks still read Ytab)

    // CSR build (rank-from-count: no cursor, no scatter atomics)
    hipMemsetAsync(deg0, 0, NN * sizeof(int), stream);
    edge_count<<<EV_B, 256, 0, stream>>>(eh, deg0, rank);
    scan_local<<<SCAN_B, 256, 0, stream>>>(deg0, offsets, bsum);
    scan_add2<<<SCAN_B, 256, 0, stream>>>(offsets, bsum);

    // atomic-free edge permute (tail-only 4B scatter) || prep tables
    scatter_prep<<<EV_B + NW1_B, 256, 0, stream>>>(eh, et, rank, offsets, csr_tail,
                                                   Gu, Gi, deg0, Ytab, Ttab);

    // fused iter-0: Z-accum (LDS) + per-edge dots/softmax + deg sums + Y1i
    zat<<<N8_B, 256, 0, stream>>>(offsets, csr_tail, Ytab, Ttab, s4, dcol1,
                                  Gu, Gi, Y1i);

    // iter 1 propagate + finalize: single visit per edge, full-line gathers
    outk<<<N8_B, 256, 0, stream>>>(offsets, csr_tail, Y1i, s4, dcol1, Gu, Gi, out);
}

// Round 11
// 234.885 us; speedup vs baseline: 4.9935x; 1.0097x over previous
//
#include <hip/hip_runtime.h>
#include <hip/hip_fp16.h>

// DGCF single-layer, 2 routing iters (MI355X). fp32 in / fp32 out.
// R25: table unification. R24's zat = 69us, FETCH 155MB: random 128B row
// gathers of Ytab (phase A) + Ttab (phase B) from 7.68MB tables miss the
// 4MB per-XCD L2 (~30% hit). outk repeats this vs a third cold table Y1i
// (which we also pay 7.68MB to write). All three are scalar*X:
//   Ytab = d0[n]*X, Y1i = d1[n]*X, Ttab = tanh(invx*X).
// Keep Ttab; replace Ytab/Y1i with ONE Xh[n][64] (half X) + tiny scalars:
//   d0a[n] (240KB, computed FREE inside scan_local which already loads
//   deg0) and existing dcol1[n][4].
//  - zat-A: gather Xh[t] + broadcast d0a[t] (L2-resident), d0 in-register.
//  - outk: gathers the SAME warm Xh + broadcast dcol1[t]; y1 = d1*xh in
//    fp32 (more precise than old half-rounded Y1i). Y1i deleted
//    (-7.68MB writes, -phase C row pass). Unique gather bytes 23->15.4MB.
//  - prep (tanh-heavy) moved into edge_count dispatch (VALU overlapped
//    with atomic-latency counting); scatter now a slim pure permute.
// Unchanged (verified R24): zat LDS fusion (zn[8][72], ssum, 8-way head
// search), rank-from-count atomic-free scatter, outk 2-node x 32-lane
// full-line gathers, scans.

#define NUSERS 30000
#define NN     60000
#define EE     800000
#define SCAN_B ((NN + 255) / 256)       // 235 scan blocks
#define EV_B   ((EE / 4 + 255) / 256)   // 782 int4 edge blocks
#define NW1_B  ((NN + 1 + 3) / 4)       // 15001 prep node blocks (incl zero row)
#define N8_B   (NN / 8)                 // 7500 blocks (8 nodes; 8 | NN)

__device__ __forceinline__ float getX(const float* __restrict__ Gu,
                                      const float* __restrict__ Gi,
                                      int n, int c) {
    return (n < NUSERS) ? Gu[n * 64 + c] : Gi[(n - NUSERS) * 64 + c];
}

__device__ __forceinline__ int clampN(int n) {
    return ((unsigned)n < (unsigned)NN) ? n : 0;
}

__device__ __forceinline__ __half2 bch2(float f) {
    return __builtin_bit_cast(__half2, f);
}

// ---- merged dispatch: edge_count (blocks [0,EV_B)) || prep (rest) ----
// count: degrees + per-edge rank (atomicAdd return), rank stored int4.
// prep: Xh[n][64] = half(X row), Ttab[n][64] = tanh(l2norm-per-intent X).
// prep does NOT read deg0 -> no hazard with counting atomics.
__global__ void count_prep(const int* __restrict__ eh, int* __restrict__ deg0,
                           int* __restrict__ rank,
                           const float* __restrict__ Gu, const float* __restrict__ Gi,
                           __half* __restrict__ Xh, __half* __restrict__ Ttab) {
    if (blockIdx.x < EV_B) {
        int e4 = (blockIdx.x * 256 + threadIdx.x) * 4;
        if (e4 >= EE) return;
        int4 h = *(const int4*)(eh + e4);
        int4 r;
        r.x = atomicAdd(&deg0[clampN(h.x)], 1);
        r.y = atomicAdd(&deg0[clampN(h.y)], 1);
        r.z = atomicAdd(&deg0[clampN(h.z)], 1);
        r.w = atomicAdd(&deg0[clampN(h.w)], 1);
        *(int4*)(rank + e4) = r;
    } else {
        int n = (blockIdx.x - EV_B) * 4 + (threadIdx.x >> 6);
        if (n > NN) return;                     // zero row at n == NN
        int lane = threadIdx.x & 63;            // lane == channel c
        float x = (n < NN) ? getX(Gu, Gi, n, lane) : 0.f;
        float sx = x * x;
        #pragma unroll
        for (int m = 1; m < 16; m <<= 1) sx += __shfl_xor(sx, m, 64);  // 16-ch intent group
        float invx = rsqrtf(fmaxf(sx, 1e-12f));
        size_t a = (size_t)n * 64 + lane;
        Xh[a]   = __float2half(x);
        Ttab[a] = __float2half(tanhf(x * invx));
    }
}

// In-block exclusive scan of 256 ints; also writes d0a (free: deg0 loaded).
__global__ void scan_local(const int* __restrict__ deg0, int* __restrict__ offsets,
                           int* __restrict__ bsum, float* __restrict__ d0a) {
    int gid = blockIdx.x * 256 + threadIdx.x;
    int lane = threadIdx.x & 63, w = threadIdx.x >> 6;
    int vdeg = (gid < NN) ? deg0[gid] : 0;
    if (gid < NN) d0a[gid] = rsqrtf(fmaxf(0.25f * (float)vdeg, 1e-30f));
    if (gid == NN) d0a[NN] = 0.f;               // zero row
    int x = vdeg;
    #pragma unroll
    for (int d = 1; d < 64; d <<= 1) {
        int y = __shfl_up(x, d, 64);
        if (lane >= d) x += y;
    }
    __shared__ int wsum[4];
    if (lane == 63) wsum[w] = x;
    __syncthreads();
    int wpre = 0;
    #pragma unroll
    for (int j = 0; j < 4; ++j) wpre += (j < w) ? wsum[j] : 0;
    int incl = x + wpre;
    if (gid < NN) offsets[gid] = incl - vdeg;
    if (threadIdx.x == 255) bsum[blockIdx.x] = incl;
}

// Each block re-scans the 235 block sums (cheap) and adds its own prefix.
__global__ void scan_add2(int* __restrict__ offsets, const int* __restrict__ bsum) {
    int tid = threadIdx.x, lane = tid & 63, w = tid >> 6;
    int vv = (tid < SCAN_B) ? bsum[tid] : 0;
    int x = vv;
    #pragma unroll
    for (int d = 1; d < 64; d <<= 1) {
        int y = __shfl_up(x, d, 64);
        if (lane >= d) x += y;
    }
    __shared__ int wsum[4];
    __shared__ int bpre;
    if (lane == 63) wsum[w] = x;
    __syncthreads();
    int wpre = 0;
    #pragma unroll
    for (int j = 0; j < 4; ++j) wpre += (j < w) ? wsum[j] : 0;
    if (tid == blockIdx.x) bpre = x + wpre - vv;   // exclusive prefix of this block
    __syncthreads();
    int gid = blockIdx.x * 256 + tid;
    if (gid < NN) offsets[gid] += bpre;
    if (gid == 0) offsets[NN] = EE;
}

// ---- scatter: atomic-free permute; ONE scattered 4B (tail) store/edge ----
__global__ void scatter(const int* __restrict__ eh, const int* __restrict__ et,
                        const int* __restrict__ rank, const int* __restrict__ offsets,
                        int* __restrict__ csr_tail) {
    int e4 = (blockIdx.x * 256 + threadIdx.x) * 4;
    if (e4 >= EE) return;
    int4 h = *(const int4*)(eh + e4);
    int4 t = *(const int4*)(et + e4);
    int4 r = *(const int4*)(rank + e4);
    int s0 = offsets[clampN(h.x)] + r.x;
    if ((unsigned)s0 < EE) csr_tail[s0] = clampN(t.x);
    int s1 = offsets[clampN(h.y)] + r.y;
    if ((unsigned)s1 < EE) csr_tail[s1] = clampN(t.y);
    int s2 = offsets[clampN(h.z)] + r.z;
    if ((unsigned)s2 < EE) csr_tail[s2] = clampN(t.z);
    int s3 = offsets[clampN(h.w)] + r.w;
    if ((unsigned)s3 < EE) csr_tail[s3] = clampN(t.w);
}

// ---- zat: fused Z-accum + per-edge dots/softmax + deg sums (8 nodes) ----
__global__ void zat(const int* __restrict__ offsets, const int* __restrict__ csr_tail,
                    const __half* __restrict__ Xh, const float* __restrict__ d0a,
                    const __half* __restrict__ Ttab,
                    __half* __restrict__ s4, float* __restrict__ dcol1) {
    __shared__ __half zn[8][72];        // 144B row stride (+16B pad: no bank confl)
    __shared__ float ssum[8][4];        // per-node per-intent score sums
    __shared__ int soff[9];
    int tid = threadIdx.x;
    int n0 = blockIdx.x * 8;            // 8 | NN, always full
    if (tid < 9) soff[tid] = offsets[n0 + tid];
    if (tid >= 32 && tid < 64) ssum[(tid - 32) >> 2][tid & 3] = 0.f;
    __syncthreads();

    // phase A: per 32-lane group, accumulate Z = sum d0[t]*Xh[t], norm -> LDS
    {
        int g = tid >> 5, cc = tid & 31;
        int s0 = soff[g], s1 = soff[g + 1];
        float accx = 0.f, accy = 0.f;
        for (int base = s0; base < s1; base += 4) {
            #pragma unroll
            for (int u = 0; u < 4; ++u) {
                int kk = base + u;
                bool act = kk < s1;
                int kc = act ? kk : s0;          // in-bounds; deg >= 1 always
                int t = act ? csr_tail[kc] : NN; // NN = zero row (Xh row = 0)
                float d0v = d0a[t];              // broadcast, L2-resident
                __half2 y = *(const __half2*)(Xh + (size_t)t * 64 + cc * 2);
                float2 yf = __half22float2(y);
                accx = fmaf(d0v, yf.x, accx);
                accy = fmaf(d0v, yf.y, accy);
            }
        }
        float ss = accx * accx + accy * accy;
        ss += __shfl_xor(ss, 1, 64);
        ss += __shfl_xor(ss, 2, 64);
        ss += __shfl_xor(ss, 4, 64);             // 8-lane group = 1 intent
        float inv = rsqrtf(fmaxf(ss, 1e-12f));
        *(__half2*)&zn[g][cc * 2] = __floats2half2_rn(accx * inv, accy * inv);
    }
    __syncthreads();

    // phase B: per-edge dots + softmax over the block's edge span
    int e0 = soff[0], e1 = soff[8];
    for (int k = e0 + tid; k < e1; k += 256) {
        int hl = 0;
        #pragma unroll
        for (int j = 1; j < 8; ++j) hl += (k >= soff[j]) ? 1 : 0;
        int t = csr_tail[k];
        const float4* tp = (const float4*)(Ttab + (size_t)t * 64);
        float dot[4];
        #pragma unroll
        for (int i = 0; i < 4; ++i) {
            float4 za = *(const float4*)&zn[hl][i * 16];
            float4 zb = *(const float4*)&zn[hl][i * 16 + 8];
            float4 ta = tp[2 * i], tb = tp[2 * i + 1];
            __half2 acc = __floats2half2_rn(0.f, 0.f);
            acc = __hfma2(bch2(za.x), bch2(ta.x), acc);
            acc = __hfma2(bch2(za.y), bch2(ta.y), acc);
            acc = __hfma2(bch2(za.z), bch2(ta.z), acc);
            acc = __hfma2(bch2(za.w), bch2(ta.w), acc);
            acc = __hfma2(bch2(zb.x), bch2(tb.x), acc);
            acc = __hfma2(bch2(zb.y), bch2(tb.y), acc);
            acc = __hfma2(bch2(zb.z), bch2(tb.z), acc);
            acc = __hfma2(bch2(zb.w), bch2(tb.w), acc);
            float2 f = __half22float2(acc);
            dot[i] = f.x + f.y;
        }
        float mx = fmaxf(fmaxf(dot[0], dot[1]), fmaxf(dot[2], dot[3]));
        float q0 = __expf(dot[0] - mx), q1 = __expf(dot[1] - mx);
        float q2 = __expf(dot[2] - mx), q3 = __expf(dot[3] - mx);
        float inv = 1.f / (q0 + q1 + q2 + q3);
        q0 *= inv; q1 *= inv; q2 *= inv; q3 *= inv;
        __half2 o01 = __floats2half2_rn(q0, q1);
        __half2 o23 = __floats2half2_rn(q2, q3);
        int2 st;
        st.x = __builtin_bit_cast(int, o01);
        st.y = __builtin_bit_cast(int, o23);
        *(int2*)(s4 + (size_t)k * 4) = st;
        atomicAdd(&ssum[hl][0], q0);
        atomicAdd(&ssum[hl][1], q1);
        atomicAdd(&ssum[hl][2], q2);
        atomicAdd(&ssum[hl][3], q3);
    }
    __syncthreads();

    // phase C: dcol1 from LDS sums (Y1i table deleted)
    if (tid < 32) {
        int nn = n0 + (tid >> 2);
        dcol1[nn * 4 + (tid & 3)] = rsqrtf(fmaxf(ssum[tid >> 2][tid & 3], 1e-30f));
    }
}

// ---- output pass: Z2 gather + finalize ----
// wave = 2 nodes x 32 half2-ch lanes. Per edge: broadcast csr_tail + s4 +
// dcol1[t] (L2-resident); 32 lanes gather one full 128B Xh row (shared,
// warm table); y1 = d1[t]*xh computed in fp32 in-register. float2 store.
__global__ void outk(const int* __restrict__ offsets, const int* __restrict__ csr_tail,
                     const __half* __restrict__ Xh, const __half* __restrict__ s4,
                     const float* __restrict__ dcol1,
                     const float* __restrict__ Gu, const float* __restrict__ Gi,
                     float* __restrict__ out) {
    int tid = threadIdx.x;
    int n = blockIdx.x * 8 + (tid >> 5);
    if (n >= NN) return;
    int cc = tid & 31;                           // half2-channel (2cc, 2cc+1)
    int i = cc >> 3;                             // intent of this lane's channels
    int s0 = offsets[n], s1 = offsets[n + 1];
    float accx = 0.f, accy = 0.f;
    for (int base = s0; base < s1; base += 4) {
        #pragma unroll
        for (int u = 0; u < 4; ++u) {
            int kk = base + u;
            bool act = kk < s1;
            int kc = act ? kk : s0;              // in-bounds; deg >= 1 always
            int t = csr_tail[kc];
            int2 raw = *(const int2*)(s4 + (size_t)kc * 4);
            int word = (cc & 16) ? raw.y : raw.x;
            unsigned short us = (unsigned short)(word >> ((cc & 8) ? 16 : 0));
            float s = act ? __half2float(__builtin_bit_cast(__half, us)) : 0.f;
            float w = s * dcol1[t * 4 + i];      // s * d1[tail][intent]
            __half2 y = *(const __half2*)(Xh + (size_t)t * 64 + cc * 2);
            float2 yf = __half22float2(y);
            accx = fmaf(w, yf.x, accx);
            accy = fmaf(w, yf.y, accy);
        }
    }
    float d = dcol1[n * 4 + i];
    int ch = cc * 2;
    const float* xr = (n < NUSERS) ? (Gu + (size_t)n * 64 + ch)
                                   : (Gi + (size_t)(n - NUSERS) * 64 + ch);
    float2 x2 = *(const float2*)xr;
    float2 o;
    o.x = 0.5f * (x2.x + d * accx);
    o.y = 0.5f * (x2.y + d * accy);
    *(float2*)(out + (size_t)n * 64 + ch) = o;
}

// ---- launch ----

extern "C" void kernel_launch(void* const* d_in, const int* in_sizes, int n_in,
                              void* d_out, int out_size, void* d_ws, size_t ws_size,
                              hipStream_t stream) {
    const float* Gu = (const float*)d_in[0];
    const float* Gi = (const float*)d_in[1];
    const int* eh = (const int*)d_in[2];
    const int* et = (const int*)d_in[3];
    float* out = (float*)d_out;

    char* p = (char*)d_ws;
    __half* s4       = (__half*)p;     p += (size_t)EE * 4 * 2;       // 6.4 MB
    int*    csr_tail = (int*)p;        p += (size_t)EE * 4;           // 3.2 MB
    int*    rank     = (int*)p;        p += (size_t)EE * 4;           // 3.2 MB
    int*    offsets  = (int*)p;        p += ((size_t)(NN + 1) * 4 + 15) / 16 * 16;
    int*    deg0     = (int*)p;        p += (size_t)NN * 4;
    int*    bsum     = (int*)p;        p += ((size_t)SCAN_B * 4 + 15) / 16 * 16;
    float*  dcol1    = (float*)p;      p += (size_t)NN * 4 * 4;       // 960 KB
    float*  d0a      = (float*)p;      p += ((size_t)(NN + 1) * 4 + 15) / 16 * 16;
    __half* Xh       = (__half*)p;     p += (size_t)(NN + 1) * 64 * 2; // 7.68 MB
    __half* Ttab     = (__half*)p;     // 7.68 MB -> total ~30 MB

    // CSR build: count (+rank) overlapped with table prep (tanh VALU work)
    hipMemsetAsync(deg0, 0, NN * sizeof(int), stream);
    count_prep<<<EV_B + NW1_B, 256, 0, stream>>>(eh, deg0, rank, Gu, Gi, Xh, Ttab);
    scan_local<<<SCAN_B, 256, 0, stream>>>(deg0, offsets, bsum, d0a);
    scan_add2<<<SCAN_B, 256, 0, stream>>>(offsets, bsum);

    // atomic-free edge permute (tail-only 4B scatter)
    scatter<<<EV_B, 256, 0, stream>>>(eh, et, rank, offsets, csr_tail);

    // fused iter-0: Z-accum (LDS, d0 in-register) + dots/softmax + deg sums
    zat<<<N8_B, 256, 0, stream>>>(offsets, csr_tail, Xh, d0a, Ttab, s4, dcol1);

    // iter 1 propagate + finalize: d1 in-register, shared warm Xh table
    outk<<<N8_B, 256, 0, stream>>>(offsets, csr_tail, Xh, s4, dcol1, Gu, Gi, out);
}